// Round 1
// baseline (218.364 us; speedup 1.0000x reference)
//
#include <hip/hip_runtime.h>

// Shapes (fixed by the problem)
#define BN      8
#define NTOK    1024
#define DIM     512
#define INNER   512
#define CIN     128
#define SPATIAL 13824   // 24*24*24

// ---------------------------------------------------------------------------
// Kernel A: pooled[mod][b][c] = mean over 13824 spatial elems.
// One block per (mod,b,c) pair: 2*8*128 = 2048 blocks, 256 threads.
// Each block reads 54 KB contiguous as float4 -> fully coalesced.
// ---------------------------------------------------------------------------
__global__ __launch_bounds__(256) void pool_kernel(const float* __restrict__ mri,
                                                   const float* __restrict__ pet,
                                                   float* __restrict__ pooled) {
    const int blk  = blockIdx.x;        // 0..2047
    const int mod  = blk >> 10;         // 0=mri, 1=pet
    const int pair = blk & 1023;        // b*128 + c
    const float* src = (mod ? pet : mri) + (size_t)pair * SPATIAL;
    const float4* src4 = (const float4*)src;
    const int n4 = SPATIAL / 4;         // 3456

    float s = 0.f;
    for (int i = threadIdx.x; i < n4; i += 256) {
        float4 v = src4[i];
        s += v.x + v.y + v.z + v.w;
    }
    // wave-64 butterfly reduce
    #pragma unroll
    for (int off = 32; off; off >>= 1) s += __shfl_down(s, off, 64);

    __shared__ float sm[4];
    const int lane = threadIdx.x & 63, wv = threadIdx.x >> 6;
    if (lane == 0) sm[wv] = s;
    __syncthreads();
    if (threadIdx.x == 0) {
        pooled[blk] = (sm[0] + sm[1] + sm[2] + sm[3]) * (1.0f / SPATIAL);
    }
}

// ---------------------------------------------------------------------------
// Kernel B: per batch b:
//   vt[j] = sum_c Wv_mri[j,c]*pm[b,c] + Wv_pet[j,c]*pp[b,c]     (j in [0,512))
//   w[b,d] = bout[d] + sum_j Wout[d,j]*vt[j]
// 8 blocks x 512 threads. All operands tiny (L2-resident).
// ---------------------------------------------------------------------------
__global__ __launch_bounds__(512) void combine_kernel(const float* __restrict__ pooled,
                                                      const float* __restrict__ Wv_mri,
                                                      const float* __restrict__ Wv_pet,
                                                      const float* __restrict__ Wout,
                                                      const float* __restrict__ bout,
                                                      float* __restrict__ w) {
    const int b = blockIdx.x;
    const int j = threadIdx.x;          // 0..511

    __shared__ float pm[CIN], pp[CIN], vt[INNER];
    if (j < CIN) {
        pm[j] = pooled[b * CIN + j];              // mri
        pp[j] = pooled[1024 + b * CIN + j];       // pet
    }
    __syncthreads();

    float s = 0.f;
    const float4* wm4 = (const float4*)(Wv_mri + (size_t)j * CIN);
    const float4* wp4 = (const float4*)(Wv_pet + (size_t)j * CIN);
    #pragma unroll 8
    for (int c4 = 0; c4 < CIN / 4; ++c4) {
        float4 a = wm4[c4], q = wp4[c4];
        s += a.x * pm[c4*4+0] + a.y * pm[c4*4+1] + a.z * pm[c4*4+2] + a.w * pm[c4*4+3];
        s += q.x * pp[c4*4+0] + q.y * pp[c4*4+1] + q.z * pp[c4*4+2] + q.w * pp[c4*4+3];
    }
    vt[j] = s;
    __syncthreads();

    const int d = threadIdx.x;
    float acc = bout[d];
    const float4* wo4 = (const float4*)(Wout + (size_t)d * INNER);
    #pragma unroll 8
    for (int j4 = 0; j4 < INNER / 4; ++j4) {
        float4 a = wo4[j4];
        acc += a.x * vt[j4*4+0] + a.y * vt[j4*4+1] + a.z * vt[j4*4+2] + a.w * vt[j4*4+3];
    }
    w[b * DIM + d] = acc;
}

// ---------------------------------------------------------------------------
// Kernel C: out[b,n,:] = h_latent[b,n,:] + w[b,:]
// Flat float4 over 8*1024*512 = 4,194,304 elems -> 1,048,576 float4 threads.
// w is 16 KB -> L1/L2 resident broadcast.
// ---------------------------------------------------------------------------
__global__ __launch_bounds__(256) void add_kernel(const float* __restrict__ h,
                                                  const float* __restrict__ w,
                                                  float* __restrict__ out) {
    const size_t i = (size_t)blockIdx.x * 256 + threadIdx.x;  // float4 index
    const int b  = (int)(i >> 17);      // / (1024*512/4)
    const int d4 = (int)(i & 127);      // float4 index within DIM
    float4 hv = ((const float4*)h)[i];
    float4 wv = ((const float4*)(w + (size_t)b * DIM))[d4];
    float4 o = make_float4(hv.x + wv.x, hv.y + wv.y, hv.z + wv.z, hv.w + wv.w);
    ((float4*)out)[i] = o;
}

extern "C" void kernel_launch(void* const* d_in, const int* in_sizes, int n_in,
                              void* d_out, int out_size, void* d_ws, size_t ws_size,
                              hipStream_t stream) {
    const float* h_latent = (const float*)d_in[0];
    const float* h_mri    = (const float*)d_in[1];
    const float* h_pet    = (const float*)d_in[2];
    // d_in[3] = Wq    (unused: softmax over single KV token == 1, Q path dead)
    // d_in[4] = Wk_mri (unused), d_in[5] = Wk_pet (unused)
    const float* Wv_mri   = (const float*)d_in[6];
    const float* Wv_pet   = (const float*)d_in[7];
    const float* Wout     = (const float*)d_in[8];
    const float* bout     = (const float*)d_in[9];
    float* out = (float*)d_out;

    // workspace layout (floats): pooled[2][8][128] @ 0, w[8][512] @ 2048
    float* pooled = (float*)d_ws;
    float* w      = pooled + 2 * BN * CIN;

    pool_kernel<<<2 * BN * CIN, 256, 0, stream>>>(h_mri, h_pet, pooled);
    combine_kernel<<<BN, 512, 0, stream>>>(pooled, Wv_mri, Wv_pet, Wout, bout, w);
    add_kernel<<<(BN * NTOK * DIM / 4) / 256, 256, 0, stream>>>(h_latent, w, out);
}

// Round 5
// 182.215 us; speedup vs baseline: 1.1984x; 1.1984x over previous
//
#include <hip/hip_runtime.h>

// Shapes (fixed by the problem)
#define BN      8
#define NTOK    1024
#define DIM     512
#define INNER   512
#define CIN     128
#define SPATIAL 13824   // 24*24*24

// ---------------------------------------------------------------------------
// Kernel A: pooled[mod][b][c] = mean over 13824 spatial elems.
// One block per (mod,b,c): 2048 blocks, 256 threads, contiguous float4 reads.
// BW-bound: 113 MB total.
// ---------------------------------------------------------------------------
__global__ __launch_bounds__(256) void pool_kernel(const float* __restrict__ mri,
                                                   const float* __restrict__ pet,
                                                   float* __restrict__ pooled) {
    const int blk  = blockIdx.x;        // 0..2047
    const int mod  = blk >> 10;         // 0=mri, 1=pet
    const int pair = blk & 1023;        // b*128 + c
    const float* src = (mod ? pet : mri) + (size_t)pair * SPATIAL;
    const float4* src4 = (const float4*)src;
    const int n4 = SPATIAL / 4;         // 3456

    float s = 0.f;
    for (int i = threadIdx.x; i < n4; i += 256) {
        float4 v = src4[i];
        s += v.x + v.y + v.z + v.w;
    }
    #pragma unroll
    for (int off = 32; off; off >>= 1) s += __shfl_down(s, off, 64);

    __shared__ float sm[4];
    const int lane = threadIdx.x & 63, wv = threadIdx.x >> 6;
    if (lane == 0) sm[wv] = s;
    __syncthreads();
    if (threadIdx.x == 0)
        pooled[blk] = (sm[0] + sm[1] + sm[2] + sm[3]) * (1.0f / SPATIAL);
}

// ---------------------------------------------------------------------------
// Kernel B1: vt[b][j] = sum_c Wv_mri[j,c]*pm[b,c] + Wv_pet[j,c]*pp[b,c]
// 16 blocks x 256 thr: block = (b, half of j-range). 512 KB of weights,
// fully independent float4 loads per thread -> pipelines fine.
// ---------------------------------------------------------------------------
__global__ __launch_bounds__(256) void vt_kernel(const float* __restrict__ pooled,
                                                 const float* __restrict__ Wv_mri,
                                                 const float* __restrict__ Wv_pet,
                                                 float* __restrict__ vt) {
    __shared__ float pm[CIN], pp[CIN];
    const int b = blockIdx.x >> 1;                            // 0..7
    const int j = ((blockIdx.x & 1) << 8) + threadIdx.x;      // 0..511
    if (threadIdx.x < CIN)
        pm[threadIdx.x] = pooled[b * CIN + threadIdx.x];
    else if (threadIdx.x < 2 * CIN)
        pp[threadIdx.x - CIN] = pooled[BN * CIN + b * CIN + (threadIdx.x - CIN)];
    __syncthreads();

    const float4* wm4 = (const float4*)(Wv_mri + (size_t)j * CIN);
    const float4* wp4 = (const float4*)(Wv_pet + (size_t)j * CIN);
    float s = 0.f;
    #pragma unroll
    for (int c4 = 0; c4 < CIN / 4; ++c4) {
        float4 a = wm4[c4], q = wp4[c4];
        s += a.x * pm[c4*4+0] + a.y * pm[c4*4+1] + a.z * pm[c4*4+2] + a.w * pm[c4*4+3];
        s += q.x * pp[c4*4+0] + q.y * pp[c4*4+1] + q.z * pp[c4*4+2] + q.w * pp[c4*4+3];
    }
    vt[b * INNER + j] = s;
}

// ---------------------------------------------------------------------------
// Kernel B2: w[b][d] = bout[d] + Wout[d,:] . vt[b,:]
// One WAVE per d-row: 128 blocks x 256 thr (4 waves). Lane l holds
// Wout[d, l*8..l*8+7]; dot against vt for all 8 batches; butterfly reduce.
// ---------------------------------------------------------------------------
__global__ __launch_bounds__(256) void w_kernel(const float* __restrict__ vt,
                                                const float* __restrict__ Wout,
                                                const float* __restrict__ bout,
                                                float* __restrict__ w) {
    const int wv   = threadIdx.x >> 6;            // wave 0..3
    const int lane = threadIdx.x & 63;
    const int d    = blockIdx.x * 4 + wv;         // 0..511

    const float4* wo4 = (const float4*)(Wout + (size_t)d * INNER + lane * 8);
    float4 w0 = wo4[0], w1 = wo4[1];

    float acc[BN];
    #pragma unroll
    for (int b = 0; b < BN; ++b) {
        const float4* v4 = (const float4*)(vt + (size_t)b * INNER + lane * 8);
        float4 a = v4[0], c = v4[1];
        acc[b] = w0.x*a.x + w0.y*a.y + w0.z*a.z + w0.w*a.w
               + w1.x*c.x + w1.y*c.y + w1.z*c.z + w1.w*c.w;
    }
    #pragma unroll
    for (int off = 32; off; off >>= 1) {
        #pragma unroll
        for (int b = 0; b < BN; ++b) acc[b] += __shfl_xor(acc[b], off, 64);
    }
    if (lane < BN)
        w[lane * DIM + d] = acc[lane] + bout[d];
}

// ---------------------------------------------------------------------------
// Kernel C: out[b,n,:] = h_latent[b,n,:] + w[b,:]   (34 MB, BW-bound)
// ---------------------------------------------------------------------------
__global__ __launch_bounds__(256) void add_kernel(const float* __restrict__ h,
                                                  const float* __restrict__ w,
                                                  float* __restrict__ out) {
    const size_t i = (size_t)blockIdx.x * 256 + threadIdx.x;  // float4 index
    const int b  = (int)(i >> 17);      // / (1024*512/4)
    const int d4 = (int)(i & 127);      // float4 index within DIM
    float4 hv = ((const float4*)h)[i];
    float4 wv = ((const float4*)(w + (size_t)b * DIM))[d4];
    ((float4*)out)[i] = make_float4(hv.x + wv.x, hv.y + wv.y, hv.z + wv.z, hv.w + wv.w);
}

extern "C" void kernel_launch(void* const* d_in, const int* in_sizes, int n_in,
                              void* d_out, int out_size, void* d_ws, size_t ws_size,
                              hipStream_t stream) {
    const float* h_latent = (const float*)d_in[0];
    const float* h_mri    = (const float*)d_in[1];
    const float* h_pet    = (const float*)d_in[2];
    // d_in[3..5] = Wq, Wk_mri, Wk_pet — dead: softmax over a single KV token == 1.
    const float* Wv_mri   = (const float*)d_in[6];
    const float* Wv_pet   = (const float*)d_in[7];
    const float* Wout     = (const float*)d_in[8];
    const float* bout     = (const float*)d_in[9];
    float* out = (float*)d_out;

    // workspace (floats): pooled[2][8][128] @ 0, vt[8][512] @ 2048, w[8][512] @ 6144
    float* pooled = (float*)d_ws;
    float* vt     = pooled + 2 * BN * CIN;
    float* w      = vt + BN * INNER;

    pool_kernel<<<2 * BN * CIN, 256, 0, stream>>>(h_mri, h_pet, pooled);
    vt_kernel<<<2 * BN, 256, 0, stream>>>(pooled, Wv_mri, Wv_pet, vt);
    w_kernel<<<DIM / 4, 256, 0, stream>>>(vt, Wout, bout, w);
    add_kernel<<<(BN * NTOK * DIM / 4) / 256, 256, 0, stream>>>(h_latent, w, out);
}

// Round 7
// 180.170 us; speedup vs baseline: 1.2120x; 1.0113x over previous
//
#include <hip/hip_runtime.h>

// Shapes (fixed by the problem)
#define BN      8
#define NTOK    1024
#define DIM     512
#define INNER   512
#define CIN     128
#define SPATIAL 13824   // 24*24*24

// ---------------------------------------------------------------------------
// Kernel A: pooled[mod][b][c] = mean over 13824 spatial elems.
// One block per (mod,b,c): 2048 blocks, 256 threads.
// R5 profile showed VGPR_Count=8 -> only ~2 loads in flight -> latency-bound
// (40.8us, 17% HBM). Fix: 4 independent accumulators, 4 explicit loads per
// round (3 rounds of 4x256 = 3072 float4) + 384-float4 tail. 4-16 loads in
// flight per thread.
// ---------------------------------------------------------------------------
__global__ __launch_bounds__(256) void pool_kernel(const float* __restrict__ mri,
                                                   const float* __restrict__ pet,
                                                   float* __restrict__ pooled) {
    const int blk  = blockIdx.x;        // 0..2047
    const int mod  = blk >> 10;         // 0=mri, 1=pet
    const int pair = blk & 1023;        // b*128 + c
    const float4* src4 = (const float4*)((mod ? pet : mri) + (size_t)pair * SPATIAL);
    const int t = threadIdx.x;

    float s0 = 0.f, s1 = 0.f, s2 = 0.f, s3 = 0.f;
    #pragma unroll
    for (int u = 0; u < 3; ++u) {       // 3 * 1024 = 3072 float4
        const int base = u * 1024 + t;
        float4 a = src4[base];
        float4 b = src4[base + 256];
        float4 c = src4[base + 512];
        float4 d = src4[base + 768];
        s0 += a.x + a.y + a.z + a.w;
        s1 += b.x + b.y + b.z + b.w;
        s2 += c.x + c.y + c.z + c.w;
        s3 += d.x + d.y + d.z + d.w;
    }
    {   // tail: 3456 - 3072 = 384 float4
        float4 a = src4[3072 + t];
        s0 += a.x + a.y + a.z + a.w;
        if (t < 128) {
            float4 b = src4[3328 + t];
            s1 += b.x + b.y + b.z + b.w;
        }
    }
    float s = (s0 + s1) + (s2 + s3);

    #pragma unroll
    for (int off = 32; off; off >>= 1) s += __shfl_down(s, off, 64);

    __shared__ float sm[4];
    const int lane = threadIdx.x & 63, wv = threadIdx.x >> 6;
    if (lane == 0) sm[wv] = s;
    __syncthreads();
    if (threadIdx.x == 0)
        pooled[blk] = (sm[0] + sm[1] + sm[2] + sm[3]) * (1.0f / SPATIAL);
}

// ---------------------------------------------------------------------------
// Kernel B1: vt[b][j] = sum_c Wv_mri[j,c]*pm[b,c] + Wv_pet[j,c]*pp[b,c]
// 16 blocks x 256 thr: block = (b, half of j-range).
// ---------------------------------------------------------------------------
__global__ __launch_bounds__(256) void vt_kernel(const float* __restrict__ pooled,
                                                 const float* __restrict__ Wv_mri,
                                                 const float* __restrict__ Wv_pet,
                                                 float* __restrict__ vt) {
    __shared__ float pm[CIN], pp[CIN];
    const int b = blockIdx.x >> 1;                            // 0..7
    const int j = ((blockIdx.x & 1) << 8) + threadIdx.x;      // 0..511
    if (threadIdx.x < CIN)
        pm[threadIdx.x] = pooled[b * CIN + threadIdx.x];
    else if (threadIdx.x < 2 * CIN)
        pp[threadIdx.x - CIN] = pooled[BN * CIN + b * CIN + (threadIdx.x - CIN)];
    __syncthreads();

    const float4* wm4 = (const float4*)(Wv_mri + (size_t)j * CIN);
    const float4* wp4 = (const float4*)(Wv_pet + (size_t)j * CIN);
    float s = 0.f;
    #pragma unroll
    for (int c4 = 0; c4 < CIN / 4; ++c4) {
        float4 a = wm4[c4], q = wp4[c4];
        s += a.x * pm[c4*4+0] + a.y * pm[c4*4+1] + a.z * pm[c4*4+2] + a.w * pm[c4*4+3];
        s += q.x * pp[c4*4+0] + q.y * pp[c4*4+1] + q.z * pp[c4*4+2] + q.w * pp[c4*4+3];
    }
    vt[b * INNER + j] = s;
}

// ---------------------------------------------------------------------------
// Kernel B2: w[b][d] = bout[d] + Wout[d,:] . vt[b,:]
// One WAVE per d-row: 128 blocks x 256 thr (4 waves).
// ---------------------------------------------------------------------------
__global__ __launch_bounds__(256) void w_kernel(const float* __restrict__ vt,
                                                const float* __restrict__ Wout,
                                                const float* __restrict__ bout,
                                                float* __restrict__ w) {
    const int wv   = threadIdx.x >> 6;            // wave 0..3
    const int lane = threadIdx.x & 63;
    const int d    = blockIdx.x * 4 + wv;         // 0..511

    const float4* wo4 = (const float4*)(Wout + (size_t)d * INNER + lane * 8);
    float4 w0 = wo4[0], w1 = wo4[1];

    float acc[BN];
    #pragma unroll
    for (int b = 0; b < BN; ++b) {
        const float4* v4 = (const float4*)(vt + (size_t)b * INNER + lane * 8);
        float4 a = v4[0], c = v4[1];
        acc[b] = w0.x*a.x + w0.y*a.y + w0.z*a.z + w0.w*a.w
               + w1.x*c.x + w1.y*c.y + w1.z*c.z + w1.w*c.w;
    }
    #pragma unroll
    for (int off = 32; off; off >>= 1) {
        #pragma unroll
        for (int b = 0; b < BN; ++b) acc[b] += __shfl_xor(acc[b], off, 64);
    }
    if (lane < BN)
        w[lane * DIM + d] = acc[lane] + bout[d];
}

// ---------------------------------------------------------------------------
// Kernel C: out[b,n,:] = h_latent[b,n,:] + w[b,:]   (34 MB, BW-bound)
// ---------------------------------------------------------------------------
__global__ __launch_bounds__(256) void add_kernel(const float* __restrict__ h,
                                                  const float* __restrict__ w,
                                                  float* __restrict__ out) {
    const size_t i = (size_t)blockIdx.x * 256 + threadIdx.x;  // float4 index
    const int b  = (int)(i >> 17);      // / (1024*512/4)
    const int d4 = (int)(i & 127);      // float4 index within DIM
    float4 hv = ((const float4*)h)[i];
    float4 wv = ((const float4*)(w + (size_t)b * DIM))[d4];
    ((float4*)out)[i] = make_float4(hv.x + wv.x, hv.y + wv.y, hv.z + wv.z, hv.w + wv.w);
}

extern "C" void kernel_launch(void* const* d_in, const int* in_sizes, int n_in,
                              void* d_out, int out_size, void* d_ws, size_t ws_size,
                              hipStream_t stream) {
    const float* h_latent = (const float*)d_in[0];
    const float* h_mri    = (const float*)d_in[1];
    const float* h_pet    = (const float*)d_in[2];
    // d_in[3..5] = Wq, Wk_mri, Wk_pet — dead: softmax over a single KV token == 1.
    const float* Wv_mri   = (const float*)d_in[6];
    const float* Wv_pet   = (const float*)d_in[7];
    const float* Wout     = (const float*)d_in[8];
    const float* bout     = (const float*)d_in[9];
    float* out = (float*)d_out;

    // workspace (floats): pooled[2][8][128] @ 0, vt[8][512] @ 2048, w[8][512] @ 6144
    float* pooled = (float*)d_ws;
    float* vt     = pooled + 2 * BN * CIN;
    float* w      = vt + BN * INNER;

    pool_kernel<<<2 * BN * CIN, 256, 0, stream>>>(h_mri, h_pet, pooled);
    vt_kernel<<<2 * BN, 256, 0, stream>>>(pooled, Wv_mri, Wv_pet, vt);
    w_kernel<<<DIM / 4, 256, 0, stream>>>(vt, Wout, bout, w);
    add_kernel<<<(BN * NTOK * DIM / 4) / 256, 256, 0, stream>>>(h_latent, w, out);
}